// Round 12
// baseline (152.814 us; speedup 1.0000x reference)
//
#include <hip/hip_runtime.h>
#include <hip/hip_bf16.h>
#include <cstdint>

#define NN   100000
#define NE   1600000
#define FIN  512
#define FHID 32
#define FOUT 16

#define BSHIFT 8
#define BSIZE  256
#define NBUCK  391                    // ceil(100000/256)
#define HB     128                    // hist blocks (grid-stride)
#define BEPB   2048                   // edges per bin block (256 thr x 8)
#define NBB    ((NE + BEPB - 1) / BEPB) // 782
#define GEMB   391                    // gemm blocks: 4 waves x 4 tiles x 16 rows
#define TOTB   (GEMB + NBB)           // 1173

typedef float f32x4 __attribute__((ext_vector_type(4)));
typedef short s16x8 __attribute__((ext_vector_type(8)));
typedef short s16x4 __attribute__((ext_vector_type(4)));
typedef int   i32x4 __attribute__((ext_vector_type(4)));
typedef unsigned int u32;
typedef unsigned short u16;

__device__ __forceinline__ short f2bf(float f) {
  union { float f; uint32_t u; } v; v.f = f;
  uint32_t r = v.u + 0x7fffu + ((v.u >> 16) & 1u);
  return (short)(r >> 16);
}
__device__ __forceinline__ float bf2f(u16 u) {
  union { uint32_t u; float f; } v; v.u = (uint32_t)u << 16; return v.f;
}

// ---- hist (grid-stride) + last-block scan -> bstart/bcur; blk0 builds wfrag -
__global__ __launch_bounds__(256) void k_hist(const int* __restrict__ dst,
                                              const float* __restrict__ W1,
                                              u16* __restrict__ wfrag,
                                              u32* __restrict__ bcount,
                                              u32* __restrict__ ticket,
                                              u32* __restrict__ bstart,
                                              u32* __restrict__ bcur) {
  __shared__ u32 h[NBUCK];
  __shared__ u32 wsum[4];
  __shared__ bool amlast;
  int tid = threadIdx.x;
  int lane = tid & 63;

  if (blockIdx.x == 0) {
    // W1 MFMA-fragment table: wfrag[kt][nt][lane][i] (16x2x64x8 bf16 = 32 KB)
    for (int it = 0; it < 64; ++it) {
      int flat = it * 256 + tid;
      int i  = flat & 7;
      int l  = (flat >> 3) & 63;
      int nt = (flat >> 9) & 1;
      int kt = flat >> 10;
      int k  = kt * 32 + ((l >> 4) << 3) + i;
      int n  = nt * 16 + (l & 15);
      wfrag[flat] = (u16)f2bf(W1[k * 32 + n]);
    }
  }

  for (int i = tid; i < NBUCK; i += 256) h[i] = 0;
  __syncthreads();
  const int stride = HB * 256 * 4;
  for (int e0 = (blockIdx.x * 256 + tid) * 4; e0 + 3 < NE; e0 += stride) {
    i32x4 d4 = *(const i32x4*)(dst + e0);
    atomicAdd(&h[d4[0] >> BSHIFT], 1u);
    atomicAdd(&h[d4[1] >> BSHIFT], 1u);
    atomicAdd(&h[d4[2] >> BSHIFT], 1u);
    atomicAdd(&h[d4[3] >> BSHIFT], 1u);
  }
  __syncthreads();
  for (int i = tid; i < NBUCK; i += 256)
    if (h[i]) atomicAdd(&bcount[i], h[i]);
  __syncthreads();
  if (tid == 0) {
    __threadfence();
    u32 t = __hip_atomic_fetch_add(ticket, 1u, __ATOMIC_ACQ_REL, __HIP_MEMORY_SCOPE_AGENT);
    amlast = (t == gridDim.x - 1);
  }
  __syncthreads();
  if (!amlast) return;

  // exclusive scan of bcount[391]: 2 entries/thread, wave shfl scan
  u32 a0 = (2*tid   < NBUCK) ? __hip_atomic_load(&bcount[2*tid],   __ATOMIC_RELAXED, __HIP_MEMORY_SCOPE_AGENT) : 0;
  u32 a1 = (2*tid+1 < NBUCK) ? __hip_atomic_load(&bcount[2*tid+1], __ATOMIC_RELAXED, __HIP_MEMORY_SCOPE_AGENT) : 0;
  u32 s = a0 + a1;
  u32 v = s;
  #pragma unroll
  for (int off = 1; off < 64; off <<= 1) {
    u32 t = __shfl_up(v, off);
    if (lane >= off) v += t;
  }
  if (lane == 63) wsum[tid >> 6] = v;
  __syncthreads();
  if (tid < 4) {
    u32 w0 = wsum[tid], w = w0;
    #pragma unroll
    for (int off = 1; off < 4; off <<= 1) {
      u32 t = __shfl_up(w, off, 4);
      if ((tid & 3) >= off) w += t;
    }
    wsum[tid] = w - w0;
  }
  __syncthreads();
  u32 excl = v - s + wsum[tid >> 6];
  if (2*tid < NBUCK)   { bstart[2*tid]   = excl;      bcur[2*tid]   = excl; }
  if (2*tid+1 < NBUCK) { bstart[2*tid+1] = excl + a0; bcur[2*tid+1] = excl + a0; }
  if (tid == 255) bstart[NBUCK] = excl + s;
}

// ------- fused [GEMM1 | bin]: blocks [0,GEMB) gemm, [GEMB,TOTB) bin ---------
union BGSh {
  u16 Xs[4][16][512];                  // 64 KB gemm tile buffers
  struct {
    u32 cnt[NBUCK]; u32 lofs[NBUCK]; u32 gbase[NBUCK];
    u32 wsum[4]; u32 total;
    u32 stage[BEPB]; u16 sb[BEPB];
  } bin;
};

#define G1_ISSUE(TILE)                                                        \
  do {                                                                        \
    int r0_ = (TILE) * 16;                                                    \
    _Pragma("unroll")                                                         \
    for (int r_ = 0; r_ < 16; ++r_) {                                         \
      int row_ = r0_ + r_;                                                    \
      if (row_ >= NN) row_ = NN - 1;                                          \
      const float* rp_ = x + (size_t)row_ * FIN + lane * 4;                   \
      va[r_] = *(const f32x4*)rp_;                                            \
      vb[r_] = *(const f32x4*)(rp_ + 256);                                    \
    }                                                                         \
  } while (0)

#define G1_CVTWRITE()                                                         \
  do {                                                                        \
    _Pragma("unroll")                                                         \
    for (int r_ = 0; r_ < 16; ++r_) {                                         \
      u32 sw_ = (u32)((r_ & 7) << 4);                                         \
      s16x4 w0_, w1_;                                                         \
      _Pragma("unroll")                                                       \
      for (int q_ = 0; q_ < 4; ++q_) {                                        \
        w0_[q_] = f2bf(va[r_][q_]);                                           \
        w1_[q_] = f2bf(vb[r_][q_]);                                           \
      }                                                                       \
      *(s16x4*)(xw + (((u32)(r_ * 1024 + lane * 8)) ^ sw_)) = w0_;            \
      *(s16x4*)(xw + (((u32)(r_ * 1024 + 512 + lane * 8)) ^ sw_)) = w1_;      \
    }                                                                         \
  } while (0)

#define G1_MFMA_STORE(TILE)                                                   \
  do {                                                                        \
    f32x4 acc0_ = {}, acc1_ = {};                                             \
    _Pragma("unroll")                                                         \
    for (int kt_ = 0; kt_ < 16; ++kt_) {                                      \
      s16x8 af_ = *(const s16x8*)(xw +                                        \
          (((u32)(m * 1024 + kt_ * 64 + h * 16)) ^ msw));                     \
      s16x8 b0_ = wf[(kt_ * 2 + 0) * 64 + lane];                              \
      s16x8 b1_ = wf[(kt_ * 2 + 1) * 64 + lane];                              \
      acc0_ = __builtin_amdgcn_mfma_f32_16x16x32_bf16(af_, b0_, acc0_, 0,0,0);\
      acc1_ = __builtin_amdgcn_mfma_f32_16x16x32_bf16(af_, b1_, acc1_, 0,0,0);\
    }                                                                         \
    int r0_ = (TILE) * 16;                                                    \
    _Pragma("unroll")                                                         \
    for (int r_ = 0; r_ < 4; ++r_) {                                          \
      int row_ = r0_ + h * 4 + r_;                                            \
      if (row_ < NN) {                                                        \
        u16* o_ = H1 + (size_t)row_ * FHID + m;                               \
        o_[0]  = (u16)f2bf(acc0_[r_]);                                        \
        o_[16] = (u16)f2bf(acc1_[r_]);                                        \
      }                                                                       \
    }                                                                         \
  } while (0)

__global__ __launch_bounds__(256) void k_binemm(
    const int* __restrict__ src, const int* __restrict__ dst,
    const float* __restrict__ x, const u16* __restrict__ wfrag,
    u32* __restrict__ bcur, u32* __restrict__ binned,
    u16* __restrict__ H1) {
  __shared__ BGSh sh;
  const int tid = threadIdx.x;
  const int lane = tid & 63;

  if (blockIdx.x < GEMB) {
    // =================== GEMM1: H1[N,32](bf16, unscaled) ===================
    const int wv = tid >> 6;
    char* xw = (char*)&sh.Xs[wv][0][0];
    const int h = lane >> 4;
    const int m = lane & 15;
    const u32 msw = (u32)((m & 7) << 4);
    const s16x8* wf = (const s16x8*)wfrag;
    const int t0 = ((int)blockIdx.x * 4 + wv) * 4;   // 4 tiles per wave
    f32x4 va[16], vb[16];

    G1_ISSUE(t0);
    G1_CVTWRITE();
    #pragma unroll
    for (int i = 0; i < 3; ++i) {
      G1_ISSUE(t0 + i + 1);       // next tile's loads in flight
      G1_MFMA_STORE(t0 + i);      // compute current from LDS
      G1_CVTWRITE();              // drain loads, write LDS
    }
    G1_MFMA_STORE(t0 + 3);
    return;
  }

  // ======================= bin edges by bucket ============================
  const int bid = blockIdx.x - GEMB;
  for (int i = tid; i < NBUCK; i += 256) sh.bin.cnt[i] = 0;
  __syncthreads();

  int base = bid * BEPB;
  u32 vals[8]; u32 ofs[8]; int bks[8];
  #pragma unroll
  for (int half = 0; half < 2; ++half) {
    int e0 = base + tid * 8 + half * 4;
    if (e0 + 3 < NE) {
      i32x4 s4 = *(const i32x4*)(src + e0);
      i32x4 d4 = *(const i32x4*)(dst + e0);
      #pragma unroll
      for (int k = 0; k < 4; ++k) {
        int b = d4[k] >> BSHIFT;
        bks[half * 4 + k] = b;
        vals[half * 4 + k] = (u32)s4[k] | ((u32)(d4[k] & (BSIZE - 1)) << 17);
        ofs[half * 4 + k] = atomicAdd(&sh.bin.cnt[b], 1u);
      }
    } else {
      #pragma unroll
      for (int k = 0; k < 4; ++k) {
        int e = e0 + k;
        bool ok = e < NE;
        int s = 0, d = 0;
        if (ok) { s = src[e]; d = dst[e]; }
        int b = ok ? (d >> BSHIFT) : -1;
        bks[half * 4 + k] = b;
        vals[half * 4 + k] = (u32)s | ((u32)(d & (BSIZE - 1)) << 17);
        ofs[half * 4 + k] = ok ? atomicAdd(&sh.bin.cnt[b], 1u) : 0;
      }
    }
  }
  __syncthreads();

  // exclusive scan of cnt[391]: 2 entries/thread, wave shfl
  u32 a0 = (2*tid   < NBUCK) ? sh.bin.cnt[2*tid]   : 0;
  u32 a1 = (2*tid+1 < NBUCK) ? sh.bin.cnt[2*tid+1] : 0;
  u32 s = a0 + a1;
  u32 v = s;
  #pragma unroll
  for (int off = 1; off < 64; off <<= 1) {
    u32 t = __shfl_up(v, off);
    if (lane >= off) v += t;
  }
  if (lane == 63) sh.bin.wsum[tid >> 6] = v;
  __syncthreads();
  if (tid < 4) {
    u32 w0 = sh.bin.wsum[tid], w = w0;
    #pragma unroll
    for (int off = 1; off < 4; off <<= 1) {
      u32 t = __shfl_up(w, off, 4);
      if ((tid & 3) >= off) w += t;
    }
    sh.bin.wsum[tid] = w - w0;
  }
  __syncthreads();
  u32 excl = v - s + sh.bin.wsum[tid >> 6];
  if (2*tid < NBUCK) {
    sh.bin.lofs[2*tid] = excl;
    sh.bin.gbase[2*tid] = a0 ? atomicAdd(&bcur[2*tid], a0) : 0;
  }
  if (2*tid+1 < NBUCK) {
    sh.bin.lofs[2*tid+1] = excl + a0;
    sh.bin.gbase[2*tid+1] = a1 ? atomicAdd(&bcur[2*tid+1], a1) : 0;
  }
  if (tid == 255) sh.bin.total = excl + s;
  __syncthreads();
  u32 total = sh.bin.total;

  #pragma unroll
  for (int k = 0; k < 8; ++k) {
    if (bks[k] >= 0) {
      u32 sl = sh.bin.lofs[bks[k]] + ofs[k];
      sh.bin.stage[sl] = vals[k];
      sh.bin.sb[sl] = (u16)bks[k];
    }
  }
  __syncthreads();

  for (u32 s2 = tid; s2 < total; s2 += 256) {
    int b = sh.bin.sb[s2];
    binned[sh.bin.gbase[b] + (s2 - sh.bin.lofs[b])] = sh.bin.stage[s2];
  }
}

// ------- finalize per bucket: deg/dinv/rs + csr (block-local writes) --------
__global__ __launch_bounds__(256) void k_fin(const u32* __restrict__ binned,
                                             const u32* __restrict__ bstart,
                                             int* __restrict__ deg,
                                             int* __restrict__ rs,
                                             float* __restrict__ dinv,
                                             int* __restrict__ csr) {
  __shared__ u32 degl[BSIZE];
  __shared__ u32 rsl[BSIZE];
  int tid = threadIdx.x;
  int b = blockIdx.x;
  u32 start = bstart[b];
  u32 n = bstart[b + 1] - start;

  degl[tid] = 0;
  __syncthreads();
  for (u32 k = tid; k < n; k += 256)
    atomicAdd(&degl[binned[start + k] >> 17], 1u);
  __syncthreads();

  u32 v = degl[tid];
  rsl[tid] = v;
  __syncthreads();
  #pragma unroll
  for (int off = 1; off < 256; off <<= 1) {
    u32 t = (tid >= off) ? rsl[tid - off] : 0;
    __syncthreads();
    rsl[tid] += t;
    __syncthreads();
  }
  u32 e = rsl[tid] - v;   // exclusive
  __syncthreads();
  rsl[tid] = e;

  int g = b * BSIZE + tid;
  if (g < NN) {
    deg[g] = (int)v;
    rs[g] = (int)(start + e);
    dinv[g] = rsqrtf(1.0f + (float)v);
  }
  __syncthreads();

  for (u32 k = tid; k < n; k += 256) {
    u32 vv = binned[start + k];
    u32 pos = atomicAdd(&rsl[vv >> 17], 1u);
    csr[start + pos] = (int)(vv & 0x1FFFFu);
  }
}

// ------ gather1 + relu + GEMM2 fused (4 lanes/node, 8 feats, ILP-8) ---------
// h1 = relu(dd*(Σ dinv[s]*H1[s] + dd*H1[d]) + b1); Hs2 = (h1@W2)*dd  (bf16)
__global__ __launch_bounds__(256) void k_gat1(const int* __restrict__ csr,
                                              const int* __restrict__ rs,
                                              const int* __restrict__ deg,
                                              const float* __restrict__ dinv,
                                              const float* __restrict__ b1,
                                              const float* __restrict__ W2,
                                              const u16* __restrict__ H1,
                                              u16* __restrict__ Hs2) {
  __shared__ float w[FHID * FOUT];
  for (int i = threadIdx.x; i < FHID * FOUT; i += 256) w[i] = W2[i];
  __syncthreads();

  int t = blockIdx.x * 256 + threadIdx.x;
  int d = t >> 2;
  if (d >= NN) return;
  int p = t & 3;
  int start = rs[d], n = deg[d];
  float dd = dinv[d];

  float a0[8], a1[8], a2[8], a3[8];
  {
    s16x8 v = *(const s16x8*)(H1 + (size_t)d * FHID + p * 8);  // self-loop
    #pragma unroll
    for (int k = 0; k < 8; ++k) {
      a0[k] = dd * bf2f((u16)v[k]); a1[k] = 0.f; a2[k] = 0.f; a3[k] = 0.f;
    }
  }
  int j = 0;
  for (; j + 8 <= n; j += 8) {
    int s0=csr[start+j],   s1=csr[start+j+1], s2=csr[start+j+2], s3=csr[start+j+3];
    int s4=csr[start+j+4], s5=csr[start+j+5], s6=csr[start+j+6], s7=csr[start+j+7];
    float d0=dinv[s0], d1=dinv[s1], d2=dinv[s2], d3=dinv[s3];
    float d4=dinv[s4], d5=dinv[s5], d6=dinv[s6], d7=dinv[s7];
    s16x8 v0 = *(const s16x8*)(H1 + (size_t)s0 * FHID + p * 8);
    s16x8 v1 = *(const s16x8*)(H1 + (size_t)s1 * FHID + p * 8);
    s16x8 v2 = *(const s16x8*)(H1 + (size_t)s2 * FHID + p * 8);
    s16x8 v3 = *(const s16x8*)(H1 + (size_t)s3 * FHID + p * 8);
    s16x8 v4 = *(const s16x8*)(H1 + (size_t)s4 * FHID + p * 8);
    s16x8 v5 = *(const s16x8*)(H1 + (size_t)s5 * FHID + p * 8);
    s16x8 v6 = *(const s16x8*)(H1 + (size_t)s6 * FHID + p * 8);
    s16x8 v7 = *(const s16x8*)(H1 + (size_t)s7 * FHID + p * 8);
    #pragma unroll
    for (int k = 0; k < 8; ++k) {
      a0[k] = fmaf(d0, bf2f((u16)v0[k]), a0[k]);
      a1[k] = fmaf(d1, bf2f((u16)v1[k]), a1[k]);
      a2[k] = fmaf(d2, bf2f((u16)v2[k]), a2[k]);
      a3[k] = fmaf(d3, bf2f((u16)v3[k]), a3[k]);
      a0[k] = fmaf(d4, bf2f((u16)v4[k]), a0[k]);
      a1[k] = fmaf(d5, bf2f((u16)v5[k]), a1[k]);
      a2[k] = fmaf(d6, bf2f((u16)v6[k]), a2[k]);
      a3[k] = fmaf(d7, bf2f((u16)v7[k]), a3[k]);
    }
  }
  for (; j + 4 <= n; j += 4) {
    int s0=csr[start+j], s1=csr[start+j+1], s2=csr[start+j+2], s3=csr[start+j+3];
    float d0=dinv[s0], d1=dinv[s1], d2=dinv[s2], d3=dinv[s3];
    s16x8 v0 = *(const s16x8*)(H1 + (size_t)s0 * FHID + p * 8);
    s16x8 v1 = *(const s16x8*)(H1 + (size_t)s1 * FHID + p * 8);
    s16x8 v2 = *(const s16x8*)(H1 + (size_t)s2 * FHID + p * 8);
    s16x8 v3 = *(const s16x8*)(H1 + (size_t)s3 * FHID + p * 8);
    #pragma unroll
    for (int k = 0; k < 8; ++k) {
      a0[k] = fmaf(d0, bf2f((u16)v0[k]), a0[k]);
      a1[k] = fmaf(d1, bf2f((u16)v1[k]), a1[k]);
      a2[k] = fmaf(d2, bf2f((u16)v2[k]), a2[k]);
      a3[k] = fmaf(d3, bf2f((u16)v3[k]), a3[k]);
    }
  }
  for (; j < n; ++j) {
    int s0 = csr[start + j];
    float d0 = dinv[s0];
    s16x8 v0 = *(const s16x8*)(H1 + (size_t)s0 * FHID + p * 8);
    #pragma unroll
    for (int k = 0; k < 8; ++k) a0[k] = fmaf(d0, bf2f((u16)v0[k]), a0[k]);
  }

  float h[8];
  #pragma unroll
  for (int k = 0; k < 8; ++k)
    h[k] = fmaxf(((a0[k] + a1[k]) + (a2[k] + a3[k])) * dd + b1[p * 8 + k], 0.0f);

  float pj[FOUT];
  #pragma unroll
  for (int jj = 0; jj < FOUT; ++jj) pj[jj] = 0.f;
  #pragma unroll
  for (int k = 0; k < 8; ++k)
    #pragma unroll
    for (int jj = 0; jj < FOUT; ++jj)
      pj[jj] = fmaf(h[k], w[(p * 8 + k) * FOUT + jj], pj[jj]);
  #pragma unroll
  for (int jj = 0; jj < FOUT; ++jj) {
    pj[jj] += __shfl_xor(pj[jj], 1);
    pj[jj] += __shfl_xor(pj[jj], 2);
  }
  s16x4 o;
  #pragma unroll
  for (int q = 0; q < 4; ++q) o[q] = f2bf(pj[p * 4 + q] * dd);
  *(s16x4*)(Hs2 + (size_t)d * FOUT + p * 4) = o;
}

// ------ gather2 + bias + log_softmax (4 lanes/node, 4 feats, ILP-8) ---------
__global__ __launch_bounds__(256) void k_gat2(const int* __restrict__ csr,
                                              const int* __restrict__ rs,
                                              const int* __restrict__ deg,
                                              const float* __restrict__ dinv,
                                              const float* __restrict__ b2,
                                              const u16* __restrict__ Hs2,
                                              float* __restrict__ out) {
  int t = blockIdx.x * 256 + threadIdx.x;
  int d = t >> 2;
  if (d >= NN) return;
  int p = t & 3;
  int start = rs[d], n = deg[d];

  float a0[4], a1[4], a2[4], a3[4];
  {
    s16x4 v = *(const s16x4*)(Hs2 + (size_t)d * FOUT + p * 4);
    #pragma unroll
    for (int k = 0; k < 4; ++k) { a0[k] = bf2f((u16)v[k]); a1[k]=0.f; a2[k]=0.f; a3[k]=0.f; }
  }
  int j = 0;
  for (; j + 8 <= n; j += 8) {
    int s0=csr[start+j],   s1=csr[start+j+1], s2=csr[start+j+2], s3=csr[start+j+3];
    int s4=csr[start+j+4], s5=csr[start+j+5], s6=csr[start+j+6], s7=csr[start+j+7];
    s16x4 v0 = *(const s16x4*)(Hs2 + (size_t)s0 * FOUT + p * 4);
    s16x4 v1 = *(const s16x4*)(Hs2 + (size_t)s1 * FOUT + p * 4);
    s16x4 v2 = *(const s16x4*)(Hs2 + (size_t)s2 * FOUT + p * 4);
    s16x4 v3 = *(const s16x4*)(Hs2 + (size_t)s3 * FOUT + p * 4);
    s16x4 v4 = *(const s16x4*)(Hs2 + (size_t)s4 * FOUT + p * 4);
    s16x4 v5 = *(const s16x4*)(Hs2 + (size_t)s5 * FOUT + p * 4);
    s16x4 v6 = *(const s16x4*)(Hs2 + (size_t)s6 * FOUT + p * 4);
    s16x4 v7 = *(const s16x4*)(Hs2 + (size_t)s7 * FOUT + p * 4);
    #pragma unroll
    for (int k = 0; k < 4; ++k) {
      a0[k] += bf2f((u16)v0[k]); a1[k] += bf2f((u16)v1[k]);
      a2[k] += bf2f((u16)v2[k]); a3[k] += bf2f((u16)v3[k]);
      a0[k] += bf2f((u16)v4[k]); a1[k] += bf2f((u16)v5[k]);
      a2[k] += bf2f((u16)v6[k]); a3[k] += bf2f((u16)v7[k]);
    }
  }
  for (; j + 4 <= n; j += 4) {
    int s0=csr[start+j], s1=csr[start+j+1], s2=csr[start+j+2], s3=csr[start+j+3];
    s16x4 v0 = *(const s16x4*)(Hs2 + (size_t)s0 * FOUT + p * 4);
    s16x4 v1 = *(const s16x4*)(Hs2 + (size_t)s1 * FOUT + p * 4);
    s16x4 v2 = *(const s16x4*)(Hs2 + (size_t)s2 * FOUT + p * 4);
    s16x4 v3 = *(const s16x4*)(Hs2 + (size_t)s3 * FOUT + p * 4);
    #pragma unroll
    for (int k = 0; k < 4; ++k) {
      a0[k] += bf2f((u16)v0[k]); a1[k] += bf2f((u16)v1[k]);
      a2[k] += bf2f((u16)v2[k]); a3[k] += bf2f((u16)v3[k]);
    }
  }
  for (; j < n; ++j) {
    int s0 = csr[start + j];
    s16x4 v0 = *(const s16x4*)(Hs2 + (size_t)s0 * FOUT + p * 4);
    #pragma unroll
    for (int k = 0; k < 4; ++k) a0[k] += bf2f((u16)v0[k]);
  }

  float dd = dinv[d];
  float z[4];
  #pragma unroll
  for (int k = 0; k < 4; ++k)
    z[k] = ((a0[k]+a1[k]) + (a2[k]+a3[k])) * dd + b2[p * 4 + k];

  float m = fmaxf(fmaxf(z[0], z[1]), fmaxf(z[2], z[3]));
  m = fmaxf(m, __shfl_xor(m, 1));
  m = fmaxf(m, __shfl_xor(m, 2));
  float s = expf(z[0]-m) + expf(z[1]-m) + expf(z[2]-m) + expf(z[3]-m);
  s += __shfl_xor(s, 1);
  s += __shfl_xor(s, 2);
  float lse = m + logf(s);

  f32x4 o = { z[0]-lse, z[1]-lse, z[2]-lse, z[3]-lse };
  *(f32x4*)(out + (size_t)d * FOUT + p * 4) = o;
}

extern "C" void kernel_launch(void* const* d_in, const int* in_sizes, int n_in,
                              void* d_out, int out_size, void* d_ws, size_t ws_size,
                              hipStream_t stream) {
  const float* x  = (const float*)d_in[0];
  const float* W1 = (const float*)d_in[1];
  const float* b1 = (const float*)d_in[2];
  const float* W2 = (const float*)d_in[3];
  const float* b2 = (const float*)d_in[4];
  const int*   ei = (const int*)d_in[5];
  const int* srcv = ei;
  const int* dstv = ei + NE;

  char* ws = (char*)d_ws;
  const size_t KB = 1024, MB = 1048576;
  u32*   bcount = (u32*)(ws + 0);           // 1564 B
  u32*   ticket = (u32*)(ws + 1600);        // 4 B
  u32*   bstart = (u32*)(ws + 8 * KB);      // 1568 B
  u32*   bcur   = (u32*)(ws + 16 * KB);     // 1564 B
  u16*   wfrag  = (u16*)(ws + 64 * KB);     // 32 KB W1 fragment table
  int*   deg    = (int*)(ws + 512 * KB);    // 0.4 MB
  int*   rs     = (int*)(ws + 1024 * KB);   // 0.4 MB
  float* dinv   = (float*)(ws + 1536 * KB); // 0.4 MB
  u32*   binned = (u32*)(ws + 2 * MB);      // 6.4 MB
  int*   csr    = (int*)(ws + 9 * MB);      // 6.4 MB
  u16*   H1     = (u16*)(ws + 16 * MB);     // 6.4 MB (bf16, unscaled)
  u16*   Hs2    = (u16*)(ws + 23 * MB);     // 3.2 MB (bf16)
  float* out    = (float*)d_out;

  hipMemsetAsync(ws, 0, 2 * KB, stream);    // bcount + ticket

  k_hist  <<<HB,   256, 0, stream>>>(dstv, W1, wfrag, bcount, ticket, bstart, bcur);
  k_binemm<<<TOTB, 256, 0, stream>>>(srcv, dstv, x, wfrag, bcur, binned, H1);
  k_fin   <<<NBUCK, 256, 0, stream>>>(binned, bstart, deg, rs, dinv, csr);
  k_gat1  <<<(NN * 4 + 255) / 256, 256, 0, stream>>>(csr, rs, deg, dinv, b1, W2, H1, Hs2);
  k_gat2  <<<(NN * 4 + 255) / 256, 256, 0, stream>>>(csr, rs, deg, dinv, b2, Hs2, out);
}

// Round 13
// 133.636 us; speedup vs baseline: 1.1435x; 1.1435x over previous
//
#include <hip/hip_runtime.h>
#include <hip/hip_bf16.h>
#include <cstdint>

#define NN   100000
#define NE   1600000
#define FIN  512
#define FHID 32
#define FOUT 16

#define BSHIFT 8
#define BSIZE  256
#define NBUCK  391                    // ceil(100000/256)
#define HB     128                    // hist blocks (grid-stride)
#define BEPB   4096                   // edges per bin block (512 thr x 8)
#define NBB    ((NE + BEPB - 1) / BEPB) // 391
#define GB     3125                   // gemm1 blocks: 1 wave x 2 tiles x 16 rows

typedef float f32x4 __attribute__((ext_vector_type(4)));
typedef short s16x8 __attribute__((ext_vector_type(8)));
typedef short s16x4 __attribute__((ext_vector_type(4)));
typedef int   i32x4 __attribute__((ext_vector_type(4)));
typedef unsigned int u32;
typedef unsigned short u16;

__device__ __forceinline__ short f2bf(float f) {
  union { float f; uint32_t u; } v; v.f = f;
  uint32_t r = v.u + 0x7fffu + ((v.u >> 16) & 1u);
  return (short)(r >> 16);
}
__device__ __forceinline__ float bf2f(u16 u) {
  union { uint32_t u; float f; } v; v.u = (uint32_t)u << 16; return v.f;
}

// ---- hist (grid-stride) + last-block scan -> bstart/bcur; blk0 builds wfrag -
__global__ __launch_bounds__(256) void k_hist(const int* __restrict__ dst,
                                              const float* __restrict__ W1,
                                              u16* __restrict__ wfrag,
                                              u32* __restrict__ bcount,
                                              u32* __restrict__ ticket,
                                              u32* __restrict__ bstart,
                                              u32* __restrict__ bcur) {
  __shared__ u32 h[NBUCK];
  __shared__ u32 wsum[4];
  __shared__ bool amlast;
  int tid = threadIdx.x;
  int lane = tid & 63;

  if (blockIdx.x == 0) {
    // W1 MFMA-fragment table: wfrag[kt][nt][lane][i] (16x2x64x8 bf16 = 32 KB)
    for (int it = 0; it < 64; ++it) {
      int flat = it * 256 + tid;
      int i  = flat & 7;
      int l  = (flat >> 3) & 63;
      int nt = (flat >> 9) & 1;
      int kt = flat >> 10;
      int k  = kt * 32 + ((l >> 4) << 3) + i;
      int n  = nt * 16 + (l & 15);
      wfrag[flat] = (u16)f2bf(W1[k * 32 + n]);
    }
  }

  for (int i = tid; i < NBUCK; i += 256) h[i] = 0;
  __syncthreads();
  const int stride = HB * 256 * 4;
  for (int e0 = (blockIdx.x * 256 + tid) * 4; e0 + 3 < NE; e0 += stride) {
    i32x4 d4 = *(const i32x4*)(dst + e0);
    atomicAdd(&h[d4[0] >> BSHIFT], 1u);
    atomicAdd(&h[d4[1] >> BSHIFT], 1u);
    atomicAdd(&h[d4[2] >> BSHIFT], 1u);
    atomicAdd(&h[d4[3] >> BSHIFT], 1u);
  }
  __syncthreads();
  for (int i = tid; i < NBUCK; i += 256)
    if (h[i]) atomicAdd(&bcount[i], h[i]);
  __syncthreads();
  if (tid == 0) {
    __threadfence();
    u32 t = __hip_atomic_fetch_add(ticket, 1u, __ATOMIC_ACQ_REL, __HIP_MEMORY_SCOPE_AGENT);
    amlast = (t == gridDim.x - 1);
  }
  __syncthreads();
  if (!amlast) return;

  // exclusive scan of bcount[391]: 2 entries/thread, wave shfl scan
  u32 a0 = (2*tid   < NBUCK) ? __hip_atomic_load(&bcount[2*tid],   __ATOMIC_RELAXED, __HIP_MEMORY_SCOPE_AGENT) : 0;
  u32 a1 = (2*tid+1 < NBUCK) ? __hip_atomic_load(&bcount[2*tid+1], __ATOMIC_RELAXED, __HIP_MEMORY_SCOPE_AGENT) : 0;
  u32 s = a0 + a1;
  u32 v = s;
  #pragma unroll
  for (int off = 1; off < 64; off <<= 1) {
    u32 t = __shfl_up(v, off);
    if (lane >= off) v += t;
  }
  if (lane == 63) wsum[tid >> 6] = v;
  __syncthreads();
  if (tid < 4) {
    u32 w0 = wsum[tid], w = w0;
    #pragma unroll
    for (int off = 1; off < 4; off <<= 1) {
      u32 t = __shfl_up(w, off, 4);
      if ((tid & 3) >= off) w += t;
    }
    wsum[tid] = w - w0;
  }
  __syncthreads();
  u32 excl = v - s + wsum[tid >> 6];
  if (2*tid < NBUCK)   { bstart[2*tid]   = excl;      bcur[2*tid]   = excl; }
  if (2*tid+1 < NBUCK) { bstart[2*tid+1] = excl + a0; bcur[2*tid+1] = excl + a0; }
  if (tid == 255) bstart[NBUCK] = excl + s;
}

// ---------------- bin edges by bucket, coalesced writes ---------------------
__global__ __launch_bounds__(512) void k_bin(const int* __restrict__ src,
                                             const int* __restrict__ dst,
                                             u32* __restrict__ bcur,
                                             u32* __restrict__ binned) {
  __shared__ u32 cnt[NBUCK];
  __shared__ u32 lofs[NBUCK];
  __shared__ u32 gbase[NBUCK];
  __shared__ u32 tmp[512];
  __shared__ u32 stage[BEPB];
  __shared__ u16 sb[BEPB];
  int tid = threadIdx.x;
  for (int i = tid; i < NBUCK; i += 512) cnt[i] = 0;
  __syncthreads();

  int base = blockIdx.x * BEPB;
  u32 vals[8]; u32 ofs[8]; int bks[8];
  #pragma unroll
  for (int half = 0; half < 2; ++half) {
    int e0 = base + tid * 8 + half * 4;
    if (e0 + 3 < NE) {
      i32x4 s4 = *(const i32x4*)(src + e0);
      i32x4 d4 = *(const i32x4*)(dst + e0);
      #pragma unroll
      for (int k = 0; k < 4; ++k) {
        int b = d4[k] >> BSHIFT;
        bks[half * 4 + k] = b;
        vals[half * 4 + k] = (u32)s4[k] | ((u32)(d4[k] & (BSIZE - 1)) << 17);
        ofs[half * 4 + k] = atomicAdd(&cnt[b], 1u);
      }
    } else {
      #pragma unroll
      for (int k = 0; k < 4; ++k) {
        int e = e0 + k;
        bool ok = e < NE;
        int s = 0, d = 0;
        if (ok) { s = src[e]; d = dst[e]; }
        int b = ok ? (d >> BSHIFT) : -1;
        bks[half * 4 + k] = b;
        vals[half * 4 + k] = (u32)s | ((u32)(d & (BSIZE - 1)) << 17);
        ofs[half * 4 + k] = ok ? atomicAdd(&cnt[b], 1u) : 0;
      }
    }
  }
  __syncthreads();

  u32 cv = (tid < NBUCK) ? cnt[tid] : 0;
  tmp[tid] = cv;
  __syncthreads();
  #pragma unroll
  for (int off = 1; off < 512; off <<= 1) {
    u32 t = (tid >= off) ? tmp[tid - off] : 0;
    __syncthreads();
    tmp[tid] += t;
    __syncthreads();
  }
  if (tid < NBUCK) {
    lofs[tid] = tmp[tid] - cv;
    gbase[tid] = cv ? atomicAdd(&bcur[tid], cv) : 0;
  }
  __syncthreads();
  u32 total = tmp[511];
  __syncthreads();

  #pragma unroll
  for (int k = 0; k < 8; ++k) {
    if (bks[k] >= 0) {
      u32 sl = lofs[bks[k]] + ofs[k];
      stage[sl] = vals[k];
      sb[sl] = (u16)bks[k];
    }
  }
  __syncthreads();

  for (u32 s2 = tid; s2 < total; s2 += 512) {
    int b = sb[s2];
    binned[gbase[b] + (s2 - lofs[b])] = stage[s2];
  }
}

// ------- finalize per bucket: deg/dinv/rs + csr (block-local writes) --------
__global__ __launch_bounds__(256) void k_fin(const u32* __restrict__ binned,
                                             const u32* __restrict__ bstart,
                                             int* __restrict__ deg,
                                             int* __restrict__ rs,
                                             float* __restrict__ dinv,
                                             int* __restrict__ csr) {
  __shared__ u32 degl[BSIZE];
  __shared__ u32 rsl[BSIZE];
  int tid = threadIdx.x;
  int b = blockIdx.x;
  u32 start = bstart[b];
  u32 n = bstart[b + 1] - start;

  degl[tid] = 0;
  __syncthreads();
  for (u32 k = tid; k < n; k += 256)
    atomicAdd(&degl[binned[start + k] >> 17], 1u);
  __syncthreads();

  u32 v = degl[tid];
  rsl[tid] = v;
  __syncthreads();
  #pragma unroll
  for (int off = 1; off < 256; off <<= 1) {
    u32 t = (tid >= off) ? rsl[tid - off] : 0;
    __syncthreads();
    rsl[tid] += t;
    __syncthreads();
  }
  u32 e = rsl[tid] - v;   // exclusive
  __syncthreads();
  rsl[tid] = e;

  int g = b * BSIZE + tid;
  if (g < NN) {
    deg[g] = (int)v;
    rs[g] = (int)(start + e);
    dinv[g] = rsqrtf(1.0f + (float)v);
  }
  __syncthreads();

  for (u32 k = tid; k < n; k += 256) {
    u32 vv = binned[start + k];
    u32 pos = atomicAdd(&rsl[vv >> 17], 1u);
    csr[start + pos] = (int)(vv & 0x1FFFFu);
  }
}

// ------- GEMM1: Hs1[N,32](bf16) = (x[N,512] @ W1) * dinv[row] ---------------
// One wave per block, 2 tiles; COLUMN-HALF rolling pipeline with a single
// 64-VGPR buffer: issue(half i+1) -> MFMA(half i, from LDS) -> cvt(half i+1).
// Loads are in flight during every MFMA phase; ~110 VGPR, 16KB LDS -> 10
// waves/CU.  kt 0-7 reads only cols 0-255 (half 0), kt 8-15 cols 256-511.
#define G1_ISSUE(TILE, HALF)                                                  \
  do {                                                                        \
    int r0_ = (TILE) * 16;                                                    \
    _Pragma("unroll")                                                         \
    for (int r_ = 0; r_ < 16; ++r_) {                                         \
      buf[r_] = *(const f32x4*)(x + (size_t)(r0_ + r_) * FIN +                \
                                (HALF) * 256 + lane * 4);                     \
    }                                                                         \
  } while (0)

#define G1_CVT(HALF)                                                          \
  do {                                                                        \
    _Pragma("unroll")                                                         \
    for (int r_ = 0; r_ < 16; ++r_) {                                         \
      u32 sw_ = (u32)((r_ & 7) << 4);                                         \
      s16x4 w_;                                                               \
      _Pragma("unroll")                                                       \
      for (int q_ = 0; q_ < 4; ++q_) w_[q_] = f2bf(buf[r_][q_]);              \
      *(s16x4*)(xw + (((u32)(r_ * 1024 + (HALF) * 512 + lane * 8)) ^ sw_)) = w_; \
    }                                                                         \
  } while (0)

#define G1_MFMAH(HALF)                                                        \
  do {                                                                        \
    _Pragma("unroll")                                                         \
    for (int kt_ = (HALF) * 8; kt_ < (HALF) * 8 + 8; ++kt_) {                 \
      s16x8 af_ = *(const s16x8*)(xw +                                        \
          (((u32)(m * 1024 + kt_ * 64 + h * 16)) ^ msw));                     \
      s16x8 b0_ = wf[(kt_ * 2 + 0) * 64 + lane];                              \
      s16x8 b1_ = wf[(kt_ * 2 + 1) * 64 + lane];                              \
      acc0 = __builtin_amdgcn_mfma_f32_16x16x32_bf16(af_, b0_, acc0, 0,0,0);  \
      acc1 = __builtin_amdgcn_mfma_f32_16x16x32_bf16(af_, b1_, acc1, 0,0,0);  \
    }                                                                         \
  } while (0)

#define G1_STORE(TILE)                                                        \
  do {                                                                        \
    int r0_ = (TILE) * 16;                                                    \
    _Pragma("unroll")                                                         \
    for (int r_ = 0; r_ < 4; ++r_) {                                          \
      int row_ = r0_ + h * 4 + r_;                                            \
      float di_ = dinv[row_];                                                 \
      u16* o_ = Hs1 + (size_t)row_ * FHID + m;                                \
      o_[0]  = (u16)f2bf(acc0[r_] * di_);                                     \
      o_[16] = (u16)f2bf(acc1[r_] * di_);                                     \
    }                                                                         \
  } while (0)

__global__ __launch_bounds__(64) void k_gemm1(const float* __restrict__ x,
                                              const u16* __restrict__ wfrag,
                                              const float* __restrict__ dinv,
                                              u16* __restrict__ Hs1) {
  __shared__ u16 Xs[16][512];          // 16 KB, one tile (both halves)
  const int lane = threadIdx.x;        // 0..63 (one wave)
  char* xw = (char*)Xs;
  const int h = lane >> 4;
  const int m = lane & 15;
  const u32 msw = (u32)((m & 7) << 4);
  const s16x8* wf = (const s16x8*)wfrag;
  const int t0 = blockIdx.x * 2;       // NN = 6250*16 exactly, 3125 blocks

  f32x4 buf[16];
  f32x4 acc0, acc1;

  G1_ISSUE(t0, 0);   G1_CVT(0);
  G1_ISSUE(t0, 1);   acc0 = (f32x4){}; acc1 = (f32x4){};
                     G1_MFMAH(0);  G1_CVT(1);
  G1_ISSUE(t0+1, 0); G1_MFMAH(1);  G1_STORE(t0);  G1_CVT(0);
  G1_ISSUE(t0+1, 1); acc0 = (f32x4){}; acc1 = (f32x4){};
                     G1_MFMAH(0);  G1_CVT(1);
                     G1_MFMAH(1);  G1_STORE(t0+1);
}

// ------ gather1 + relu + GEMM2 fused (4 lanes/node, 8 feats, ILP-8) ---------
__global__ __launch_bounds__(256) void k_gat1(const int* __restrict__ csr,
                                              const int* __restrict__ rs,
                                              const int* __restrict__ deg,
                                              const float* __restrict__ dinv,
                                              const float* __restrict__ b1,
                                              const float* __restrict__ W2,
                                              const u16* __restrict__ Hs1,
                                              u16* __restrict__ Hs2) {
  __shared__ float w[FHID * FOUT];
  for (int i = threadIdx.x; i < FHID * FOUT; i += 256) w[i] = W2[i];
  __syncthreads();

  int t = blockIdx.x * 256 + threadIdx.x;
  int d = t >> 2;
  if (d >= NN) return;
  int p = t & 3;
  int start = rs[d], n = deg[d];

  float a0[8], a1[8], a2[8], a3[8];
  {
    s16x8 v = *(const s16x8*)(Hs1 + (size_t)d * FHID + p * 8);  // self-loop
    #pragma unroll
    for (int k = 0; k < 8; ++k) {
      a0[k] = bf2f((u16)v[k]); a1[k] = 0.f; a2[k] = 0.f; a3[k] = 0.f;
    }
  }
  int j = 0;
  for (; j + 8 <= n; j += 8) {
    int s0=csr[start+j],   s1=csr[start+j+1], s2=csr[start+j+2], s3=csr[start+j+3];
    int s4=csr[start+j+4], s5=csr[start+j+5], s6=csr[start+j+6], s7=csr[start+j+7];
    s16x8 v0 = *(const s16x8*)(Hs1 + (size_t)s0 * FHID + p * 8);
    s16x8 v1 = *(const s16x8*)(Hs1 + (size_t)s1 * FHID + p * 8);
    s16x8 v2 = *(const s16x8*)(Hs1 + (size_t)s2 * FHID + p * 8);
    s16x8 v3 = *(const s16x8*)(Hs1 + (size_t)s3 * FHID + p * 8);
    s16x8 v4 = *(const s16x8*)(Hs1 + (size_t)s4 * FHID + p * 8);
    s16x8 v5 = *(const s16x8*)(Hs1 + (size_t)s5 * FHID + p * 8);
    s16x8 v6 = *(const s16x8*)(Hs1 + (size_t)s6 * FHID + p * 8);
    s16x8 v7 = *(const s16x8*)(Hs1 + (size_t)s7 * FHID + p * 8);
    #pragma unroll
    for (int k = 0; k < 8; ++k) {
      a0[k] += bf2f((u16)v0[k]);
      a1[k] += bf2f((u16)v1[k]);
      a2[k] += bf2f((u16)v2[k]);
      a3[k] += bf2f((u16)v3[k]);
      a0[k] += bf2f((u16)v4[k]);
      a1[k] += bf2f((u16)v5[k]);
      a2[k] += bf2f((u16)v6[k]);
      a3[k] += bf2f((u16)v7[k]);
    }
  }
  for (; j + 4 <= n; j += 4) {
    int s0=csr[start+j], s1=csr[start+j+1], s2=csr[start+j+2], s3=csr[start+j+3];
    s16x8 v0 = *(const s16x8*)(Hs1 + (size_t)s0 * FHID + p * 8);
    s16x8 v1 = *(const s16x8*)(Hs1 + (size_t)s1 * FHID + p * 8);
    s16x8 v2 = *(const s16x8*)(Hs1 + (size_t)s2 * FHID + p * 8);
    s16x8 v3 = *(const s16x8*)(Hs1 + (size_t)s3 * FHID + p * 8);
    #pragma unroll
    for (int k = 0; k < 8; ++k) {
      a0[k] += bf2f((u16)v0[k]);
      a1[k] += bf2f((u16)v1[k]);
      a2[k] += bf2f((u16)v2[k]);
      a3[k] += bf2f((u16)v3[k]);
    }
  }
  for (; j < n; ++j) {
    int s0 = csr[start + j];
    s16x8 v0 = *(const s16x8*)(Hs1 + (size_t)s0 * FHID + p * 8);
    #pragma unroll
    for (int k = 0; k < 8; ++k) a0[k] += bf2f((u16)v0[k]);
  }

  float dd = dinv[d];
  float h[8];
  #pragma unroll
  for (int k = 0; k < 8; ++k)
    h[k] = fmaxf(((a0[k] + a1[k]) + (a2[k] + a3[k])) * dd + b1[p * 8 + k], 0.0f);

  float pj[FOUT];
  #pragma unroll
  for (int jj = 0; jj < FOUT; ++jj) pj[jj] = 0.f;
  #pragma unroll
  for (int k = 0; k < 8; ++k)
    #pragma unroll
    for (int jj = 0; jj < FOUT; ++jj)
      pj[jj] = fmaf(h[k], w[(p * 8 + k) * FOUT + jj], pj[jj]);
  #pragma unroll
  for (int jj = 0; jj < FOUT; ++jj) {
    pj[jj] += __shfl_xor(pj[jj], 1);
    pj[jj] += __shfl_xor(pj[jj], 2);
  }
  s16x4 o;
  #pragma unroll
  for (int q = 0; q < 4; ++q) o[q] = f2bf(pj[p * 4 + q] * dd);
  *(s16x4*)(Hs2 + (size_t)d * FOUT + p * 4) = o;
}

// ------ gather2 + bias + log_softmax (4 lanes/node, 4 feats, ILP-8) ---------
__global__ __launch_bounds__(256) void k_gat2(const int* __restrict__ csr,
                                              const int* __restrict__ rs,
                                              const int* __restrict__ deg,
                                              const float* __restrict__ dinv,
                                              const float* __restrict__ b2,
                                              const u16* __restrict__ Hs2,
                                              float* __restrict__ out) {
  int t = blockIdx.x * 256 + threadIdx.x;
  int d = t >> 2;
  if (d >= NN) return;
  int p = t & 3;
  int start = rs[d], n = deg[d];

  float a0[4], a1[4], a2[4], a3[4];
  {
    s16x4 v = *(const s16x4*)(Hs2 + (size_t)d * FOUT + p * 4);
    #pragma unroll
    for (int k = 0; k < 4; ++k) { a0[k] = bf2f((u16)v[k]); a1[k]=0.f; a2[k]=0.f; a3[k]=0.f; }
  }
  int j = 0;
  for (; j + 8 <= n; j += 8) {
    int s0=csr[start+j],   s1=csr[start+j+1], s2=csr[start+j+2], s3=csr[start+j+3];
    int s4=csr[start+j+4], s5=csr[start+j+5], s6=csr[start+j+6], s7=csr[start+j+7];
    s16x4 v0 = *(const s16x4*)(Hs2 + (size_t)s0 * FOUT + p * 4);
    s16x4 v1 = *(const s16x4*)(Hs2 + (size_t)s1 * FOUT + p * 4);
    s16x4 v2 = *(const s16x4*)(Hs2 + (size_t)s2 * FOUT + p * 4);
    s16x4 v3 = *(const s16x4*)(Hs2 + (size_t)s3 * FOUT + p * 4);
    s16x4 v4 = *(const s16x4*)(Hs2 + (size_t)s4 * FOUT + p * 4);
    s16x4 v5 = *(const s16x4*)(Hs2 + (size_t)s5 * FOUT + p * 4);
    s16x4 v6 = *(const s16x4*)(Hs2 + (size_t)s6 * FOUT + p * 4);
    s16x4 v7 = *(const s16x4*)(Hs2 + (size_t)s7 * FOUT + p * 4);
    #pragma unroll
    for (int k = 0; k < 4; ++k) {
      a0[k] += bf2f((u16)v0[k]); a1[k] += bf2f((u16)v1[k]);
      a2[k] += bf2f((u16)v2[k]); a3[k] += bf2f((u16)v3[k]);
      a0[k] += bf2f((u16)v4[k]); a1[k] += bf2f((u16)v5[k]);
      a2[k] += bf2f((u16)v6[k]); a3[k] += bf2f((u16)v7[k]);
    }
  }
  for (; j + 4 <= n; j += 4) {
    int s0=csr[start+j], s1=csr[start+j+1], s2=csr[start+j+2], s3=csr[start+j+3];
    s16x4 v0 = *(const s16x4*)(Hs2 + (size_t)s0 * FOUT + p * 4);
    s16x4 v1 = *(const s16x4*)(Hs2 + (size_t)s1 * FOUT + p * 4);
    s16x4 v2 = *(const s16x4*)(Hs2 + (size_t)s2 * FOUT + p * 4);
    s16x4 v3 = *(const s16x4*)(Hs2 + (size_t)s3 * FOUT + p * 4);
    #pragma unroll
    for (int k = 0; k < 4; ++k) {
      a0[k] += bf2f((u16)v0[k]); a1[k] += bf2f((u16)v1[k]);
      a2[k] += bf2f((u16)v2[k]); a3[k] += bf2f((u16)v3[k]);
    }
  }
  for (; j < n; ++j) {
    int s0 = csr[start + j];
    s16x4 v0 = *(const s16x4*)(Hs2 + (size_t)s0 * FOUT + p * 4);
    #pragma unroll
    for (int k = 0; k < 4; ++k) a0[k] += bf2f((u16)v0[k]);
  }

  float dd = dinv[d];
  float z[4];
  #pragma unroll
  for (int k = 0; k < 4; ++k)
    z[k] = ((a0[k]+a1[k]) + (a2[k]+a3[k])) * dd + b2[p * 4 + k];

  float m = fmaxf(fmaxf(z[0], z[1]), fmaxf(z[2], z[3]));
  m = fmaxf(m, __shfl_xor(m, 1));
  m = fmaxf(m, __shfl_xor(m, 2));
  float s = expf(z[0]-m) + expf(z[1]-m) + expf(z[2]-m) + expf(z[3]-m);
  s += __shfl_xor(s, 1);
  s += __shfl_xor(s, 2);
  float lse = m + logf(s);

  f32x4 o = { z[0]-lse, z[1]-lse, z[2]-lse, z[3]-lse };
  *(f32x4*)(out + (size_t)d * FOUT + p * 4) = o;
}

extern "C" void kernel_launch(void* const* d_in, const int* in_sizes, int n_in,
                              void* d_out, int out_size, void* d_ws, size_t ws_size,
                              hipStream_t stream) {
  const float* x  = (const float*)d_in[0];
  const float* W1 = (const float*)d_in[1];
  const float* b1 = (const float*)d_in[2];
  const float* W2 = (const float*)d_in[3];
  const float* b2 = (const float*)d_in[4];
  const int*   ei = (const int*)d_in[5];
  const int* srcv = ei;
  const int* dstv = ei + NE;

  char* ws = (char*)d_ws;
  const size_t KB = 1024, MB = 1048576;
  u32*   bcount = (u32*)(ws + 0);           // 1564 B
  u32*   ticket = (u32*)(ws + 1600);        // 4 B
  u32*   bstart = (u32*)(ws + 8 * KB);      // 1568 B
  u32*   bcur   = (u32*)(ws + 16 * KB);     // 1564 B
  u16*   wfrag  = (u16*)(ws + 64 * KB);     // 32 KB W1 fragment table
  int*   deg    = (int*)(ws + 512 * KB);    // 0.4 MB
  int*   rs     = (int*)(ws + 1024 * KB);   // 0.4 MB
  float* dinv   = (float*)(ws + 1536 * KB); // 0.4 MB
  u32*   binned = (u32*)(ws + 2 * MB);      // 6.4 MB
  int*   csr    = (int*)(ws + 9 * MB);      // 6.4 MB
  u16*   Hs1    = (u16*)(ws + 16 * MB);     // 6.4 MB (bf16, scaled)
  u16*   Hs2    = (u16*)(ws + 23 * MB);     // 3.2 MB (bf16)
  float* out    = (float*)d_out;

  hipMemsetAsync(ws, 0, 2 * KB, stream);    // bcount + ticket

  k_hist <<<HB,   256, 0, stream>>>(dstv, W1, wfrag, bcount, ticket, bstart, bcur);
  k_bin  <<<NBB,  512, 0, stream>>>(srcv, dstv, bcur, binned);
  k_fin  <<<NBUCK, 256, 0, stream>>>(binned, bstart, deg, rs, dinv, csr);
  k_gemm1<<<GB, 64, 0, stream>>>(x, wfrag, dinv, Hs1);
  k_gat1 <<<(NN * 4 + 255) / 256, 256, 0, stream>>>(csr, rs, deg, dinv, b1, W2, Hs1, Hs2);
  k_gat2 <<<(NN * 4 + 255) / 256, 256, 0, stream>>>(csr, rs, deg, dinv, b2, Hs2, out);
}